// Round 1
// baseline (998.901 us; speedup 1.0000x reference)
//
#include <hip/hip_runtime.h>
#include <cstdint>
#include <cstddef>

typedef short short8 __attribute__((ext_vector_type(8)));
typedef float f32x4 __attribute__((ext_vector_type(4)));

typedef const __attribute__((address_space(1))) void* gas_ptr;
typedef __attribute__((address_space(3))) void* las_ptr;

__device__ __forceinline__ unsigned short f2bf(float f) {
    unsigned int u = __float_as_uint(f);
    u += 0x7fffu + ((u >> 16) & 1u);          // RNE (finite inputs)
    return (unsigned short)(u >> 16);
}
__device__ __forceinline__ float bf2f(unsigned short s) {
    return __uint_as_float(((unsigned int)s) << 16);
}
__device__ __forceinline__ float sigmoid_f(float z) {
    return __builtin_amdgcn_rcpf(1.0f + __expf(-z));
}
__device__ __forceinline__ void async_copy16(const void* gp, void* lp) {
    __builtin_amdgcn_global_load_lds((gas_ptr)gp, (las_ptr)lp, 16, 0, 0);
}

// ---------------- converters ----------------
// x: [32768,1024] f32 -> bf16, same layout. 8 elems/thread.
__global__ __launch_bounds__(256) void cvt_x_kernel(const float* __restrict__ in,
                                                    unsigned short* __restrict__ out) {
    size_t i = ((size_t)blockIdx.x * 256 + threadIdx.x) * 8;
    float4 v0 = *(const float4*)(in + i);
    float4 v1 = *(const float4*)(in + i + 4);
    short8 o;
    o[0]=(short)f2bf(v0.x); o[1]=(short)f2bf(v0.y); o[2]=(short)f2bf(v0.z); o[3]=(short)f2bf(v0.w);
    o[4]=(short)f2bf(v1.x); o[5]=(short)f2bf(v1.y); o[6]=(short)f2bf(v1.z); o[7]=(short)f2bf(v1.w);
    *(short8*)(out + i) = o;
}

// W: [1024,4096] f32 -> W_T bf16 [4096,1024]. 64x64 LDS tiles.
__global__ __launch_bounds__(256) void cvt_w_kernel(const float* __restrict__ W,
                                                    unsigned short* __restrict__ Wt) {
    __shared__ unsigned short tile[64][65];
    int bk = blockIdx.x >> 6, bn = blockIdx.x & 63;
    int k0 = bk * 64, n0 = bn * 64;
    int t = threadIdx.x;
    int cr = t >> 6;          // 0..3
    int cc = t & 63;          // 0..63
#pragma unroll
    for (int i = 0; i < 16; ++i) {
        int row = i * 4 + cr;
        tile[row][cc] = f2bf(W[(size_t)(k0 + row) * 4096 + n0 + cc]);
    }
    __syncthreads();
#pragma unroll
    for (int i = 0; i < 16; ++i) {
        int nrow = i * 4 + cr;
        Wt[(size_t)(n0 + nrow) * 1024 + k0 + cc] = tile[cc][nrow];
    }
}

// ---------------- GEMM ----------------
// C[m][n] = sum_k A[m][k]*B_T[n][k], m=b*1024+t (M=32768), n=j*1024+u (N=4096), K=1024.
// g (bf16) = C + bias, row-major [M][4096].
// 128x128 tile, BK=64, 4 waves in 2x2, each wave 4x4 frags of 16x16x32 bf16 MFMA.
__global__ __launch_bounds__(256, 2) void gemm_kernel(const unsigned short* __restrict__ A,
                                                      const unsigned short* __restrict__ Bt,
                                                      const float* __restrict__ bias,
                                                      unsigned short* __restrict__ g) {
    __shared__ __align__(16) unsigned short As[128 * 64];
    __shared__ __align__(16) unsigned short Bs[128 * 64];

    // band swizzle: 8 m-tiles x 32 n-tiles per band, n fastest
    int bid = blockIdx.x;
    int band = bid >> 8;
    int r = bid & 255;
    int mt = band * 8 + (r >> 5);
    int nt = r & 31;
    int m0 = mt * 128, n0 = nt * 128;

    int tidx = threadIdx.x;
    int lane = tidx & 63, wv = tidx >> 6;
    int wm = wv >> 1, wn = wv & 1;
    int l15 = lane & 15, quad = lane >> 4;

    f32x4 acc[4][4] = {};

    for (int k0 = 0; k0 < 1024; k0 += 64) {
        __syncthreads();
#pragma unroll
        for (int i = 0; i < 4; ++i) {
            int ci = (wv * 4 + i) * 64 + lane;      // 0..1023
            int row = ci >> 3, cc = ci & 7;
            int sc = (cc ^ (row & 7)) << 3;         // swizzled k-offset (elements)
            const unsigned short* ga = A + (size_t)(m0 + row) * 1024 + k0 + sc;
            async_copy16(ga, (char*)As + (wv * 4 + i) * 1024);
            const unsigned short* gb = Bt + (size_t)(n0 + row) * 1024 + k0 + sc;
            async_copy16(gb, (char*)Bs + (wv * 4 + i) * 1024);
        }
        __syncthreads();
#pragma unroll
        for (int kt = 0; kt < 2; ++kt) {
            short8 af[4], bf[4];
#pragma unroll
            for (int mt2 = 0; mt2 < 4; ++mt2) {
                int row = wm * 64 + mt2 * 16 + l15;
                int kc = kt * 4 + quad;
                af[mt2] = *(const short8*)((const char*)As + row * 128 + ((kc ^ (row & 7)) << 4));
            }
#pragma unroll
            for (int nt2 = 0; nt2 < 4; ++nt2) {
                int rown = wn * 64 + nt2 * 16 + l15;
                int kc = kt * 4 + quad;
                bf[nt2] = *(const short8*)((const char*)Bs + rown * 128 + ((kc ^ (rown & 7)) << 4));
            }
#pragma unroll
            for (int mt2 = 0; mt2 < 4; ++mt2)
#pragma unroll
                for (int nt2 = 0; nt2 < 4; ++nt2)
                    acc[mt2][nt2] = __builtin_amdgcn_mfma_f32_16x16x32_bf16(
                        af[mt2], bf[nt2], acc[mt2][nt2], 0, 0, 0);
        }
    }

    // epilogue: C/D layout col=lane&15, row=quad*4+reg
#pragma unroll
    for (int mt2 = 0; mt2 < 4; ++mt2) {
        int mbase = m0 + wm * 64 + mt2 * 16 + quad * 4;
#pragma unroll
        for (int nt2 = 0; nt2 < 4; ++nt2) {
            int n = n0 + wn * 64 + nt2 * 16 + l15;
            float bv = bias[n];
#pragma unroll
            for (int rr = 0; rr < 4; ++rr) {
                g[(size_t)(mbase + rr) * 4096 + n] = f2bf(acc[mt2][nt2][rr] + bv);
            }
        }
    }
}

// ---------------- sequential scan ----------------
// thread = one (b,u). g bf16 [B,T,4U]; h f32 [B,T,U]. 8-deep prefetch ring.
__global__ __launch_bounds__(64) void scan_kernel(const unsigned short* __restrict__ g,
                                                  const float* __restrict__ c0,
                                                  const float* __restrict__ Vr,
                                                  const float* __restrict__ Vf,
                                                  float* __restrict__ h) {
    int tid = blockIdx.x * 64 + threadIdx.x;    // 0..32767
    int b = tid >> 10, u = tid & 1023;
    const unsigned short* gb = g + (size_t)b * (1024 * 4096) + u;
    float* hb = h + (size_t)b * (1024 * 1024) + u;
    float c = c0[(b << 10) + u];
    float vf = Vf[u], vr = Vr[u];

    unsigned short r1[8], r2[8], r3[8], r4[8];
#pragma unroll
    for (int i = 0; i < 8; ++i) {
        const unsigned short* p = gb + (size_t)i * 4096;
        r1[i] = p[0]; r2[i] = p[1024]; r3[i] = p[2048]; r4[i] = p[3072];
    }
    for (int tb = 0; tb < 1024; tb += 8) {
        bool pf = (tb + 8) < 1024;
#pragma unroll
        for (int i = 0; i < 8; ++i) {
            int t = tb + i;
            float x1 = bf2f(r1[i]), x2 = bf2f(r2[i]), x3 = bf2f(r3[i]), x4 = bf2f(r4[i]);
            if (pf) {
                const unsigned short* p = gb + (size_t)(t + 8) * 4096;
                r1[i] = p[0]; r2[i] = p[1024]; r3[i] = p[2048]; r4[i] = p[3072];
            }
            float f  = sigmoid_f(x1 + vf * c);
            float cn = fmaf(f, c - x2, x2);        // f*c + (1-f)*a2
            float rr = sigmoid_f(x3 + vr * c);     // uses c_{t-1}
            float hv = fmaf(rr, cn - x4, x4);      // r*c_new + (1-r)*a4
            c = cn;
            hb[(size_t)t * 1024] = hv;
        }
    }
}

extern "C" void kernel_launch(void* const* d_in, const int* in_sizes, int n_in,
                              void* d_out, int out_size, void* d_ws, size_t ws_size,
                              hipStream_t stream) {
    const float* x  = (const float*)d_in[0];
    // d_in[1] = h0 (unused by reference)
    const float* c0 = (const float*)d_in[2];
    const float* W  = (const float*)d_in[3];
    const float* b  = (const float*)d_in[4];
    const float* Vr = (const float*)d_in[5];
    const float* Vf = (const float*)d_in[6];
    float* h = (float*)d_out;

    char* ws = (char*)d_ws;
    unsigned short* xb = (unsigned short*)ws;                         // 64 MB
    unsigned short* wt = (unsigned short*)(ws + (size_t)67108864);    // 8 MB
    unsigned short* g  = (unsigned short*)(ws + (size_t)75497472);    // 256 MB

    cvt_x_kernel<<<16384, 256, 0, stream>>>(x, xb);
    cvt_w_kernel<<<1024, 256, 0, stream>>>(W, wt);
    gemm_kernel<<<8192, 256, 0, stream>>>(xb, wt, b, g);
    scan_kernel<<<512, 64, 0, stream>>>(g, c0, Vr, Vf, h);
}

// Round 3
// 591.202 us; speedup vs baseline: 1.6896x; 1.6896x over previous
//
#include <hip/hip_runtime.h>
#include <cstdint>
#include <cstddef>

typedef short short8 __attribute__((ext_vector_type(8)));
typedef short s16x4 __attribute__((ext_vector_type(4)));
typedef float f32x4 __attribute__((ext_vector_type(4)));

typedef const __attribute__((address_space(1))) void* gas_ptr;
typedef __attribute__((address_space(3))) void* las_ptr;

__device__ __forceinline__ unsigned short f2bf(float f) {
    unsigned int u = __float_as_uint(f);
    u += 0x7fffu + ((u >> 16) & 1u);          // RNE (finite inputs)
    return (unsigned short)(u >> 16);
}
__device__ __forceinline__ float bf2f(unsigned short s) {
    return __uint_as_float(((unsigned int)s) << 16);
}
__device__ __forceinline__ float sigmoid_f(float z) {
    return __builtin_amdgcn_rcpf(1.0f + __expf(-z));
}
__device__ __forceinline__ void async_copy16(const void* gp, void* lp) {
    __builtin_amdgcn_global_load_lds((gas_ptr)gp, (las_ptr)lp, 16, 0, 0);
}

// ---------------- converters ----------------
// x: [32768,1024] f32 -> bf16, same layout. 8 elems/thread.
__global__ __launch_bounds__(256) void cvt_x_kernel(const float* __restrict__ in,
                                                    unsigned short* __restrict__ out) {
    size_t i = ((size_t)blockIdx.x * 256 + threadIdx.x) * 8;
    float4 v0 = *(const float4*)(in + i);
    float4 v1 = *(const float4*)(in + i + 4);
    short8 o;
    o[0]=(short)f2bf(v0.x); o[1]=(short)f2bf(v0.y); o[2]=(short)f2bf(v0.z); o[3]=(short)f2bf(v0.w);
    o[4]=(short)f2bf(v1.x); o[5]=(short)f2bf(v1.y); o[6]=(short)f2bf(v1.z); o[7]=(short)f2bf(v1.w);
    *(short8*)(out + i) = o;
}

// W: [1024,4096] f32 -> W_T bf16 [4096,1024]. 64x64 LDS tiles.
__global__ __launch_bounds__(256) void cvt_w_kernel(const float* __restrict__ W,
                                                    unsigned short* __restrict__ Wt) {
    __shared__ unsigned short tile[64][65];
    int bk = blockIdx.x >> 6, bn = blockIdx.x & 63;
    int k0 = bk * 64, n0 = bn * 64;
    int t = threadIdx.x;
    int cr = t >> 6;          // 0..3
    int cc = t & 63;          // 0..63
#pragma unroll
    for (int i = 0; i < 16; ++i) {
        int row = i * 4 + cr;
        tile[row][cc] = f2bf(W[(size_t)(k0 + row) * 4096 + n0 + cc]);
    }
    __syncthreads();
#pragma unroll
    for (int i = 0; i < 16; ++i) {
        int nrow = i * 4 + cr;
        Wt[(size_t)(n0 + nrow) * 1024 + k0 + cc] = tile[cc][nrow];
    }
}

// ---------------- GEMM ----------------
// C[m][n] = sum_k A[m][k]*B_T[n][k], m=b*1024+t (M=32768), n=gate*1024+u (N=4096), K=1024.
// Output: gT[gate][b][u][t] bf16 (t contiguous) = C + bias.
// 128x128 tile, BK=64, 4 waves in 2x2, each wave 4x4 frags of 16x16x32 bf16 MFMA.
__global__ __launch_bounds__(256, 2) void gemm_kernel(const unsigned short* __restrict__ A,
                                                      const unsigned short* __restrict__ Bt,
                                                      const float* __restrict__ bias,
                                                      unsigned short* __restrict__ gT) {
    __shared__ __align__(16) unsigned short As[128 * 64];
    __shared__ __align__(16) unsigned short Bs[128 * 64];

    // band swizzle: 8 m-tiles x 32 n-tiles per band, n fastest
    int bid = blockIdx.x;
    int band = bid >> 8;
    int r = bid & 255;
    int mt = band * 8 + (r >> 5);
    int nt = r & 31;
    int m0 = mt * 128, n0 = nt * 128;

    int tidx = threadIdx.x;
    int lane = tidx & 63, wv = tidx >> 6;
    int wm = wv >> 1, wn = wv & 1;
    int l15 = lane & 15, quad = lane >> 4;

    f32x4 acc[4][4] = {};

    for (int k0 = 0; k0 < 1024; k0 += 64) {
        __syncthreads();
#pragma unroll
        for (int i = 0; i < 4; ++i) {
            int ci = (wv * 4 + i) * 64 + lane;      // 0..1023
            int row = ci >> 3, cc = ci & 7;
            int sc = (cc ^ (row & 7)) << 3;         // swizzled k-offset (elements)
            const unsigned short* ga = A + (size_t)(m0 + row) * 1024 + k0 + sc;
            async_copy16(ga, (char*)As + (wv * 4 + i) * 1024);
            const unsigned short* gb = Bt + (size_t)(n0 + row) * 1024 + k0 + sc;
            async_copy16(gb, (char*)Bs + (wv * 4 + i) * 1024);
        }
        __syncthreads();
#pragma unroll
        for (int kt = 0; kt < 2; ++kt) {
            short8 af[4], bf[4];
#pragma unroll
            for (int mt2 = 0; mt2 < 4; ++mt2) {
                int row = wm * 64 + mt2 * 16 + l15;
                int kc = kt * 4 + quad;
                af[mt2] = *(const short8*)((const char*)As + row * 128 + ((kc ^ (row & 7)) << 4));
            }
#pragma unroll
            for (int nt2 = 0; nt2 < 4; ++nt2) {
                int rown = wn * 64 + nt2 * 16 + l15;
                int kc = kt * 4 + quad;
                bf[nt2] = *(const short8*)((const char*)Bs + rown * 128 + ((kc ^ (rown & 7)) << 4));
            }
#pragma unroll
            for (int mt2 = 0; mt2 < 4; ++mt2)
#pragma unroll
                for (int nt2 = 0; nt2 < 4; ++nt2)
                    acc[mt2][nt2] = __builtin_amdgcn_mfma_f32_16x16x32_bf16(
                        af[mt2], bf[nt2], acc[mt2][nt2], 0, 0, 0);
        }
    }

    // epilogue: C/D layout col=lane&15, row=quad*4+reg.
    // rr=0..3 are consecutive m => consecutive t in gT => one 8-B store.
#pragma unroll
    for (int mt2 = 0; mt2 < 4; ++mt2) {
        int mbase = m0 + wm * 64 + mt2 * 16 + quad * 4;
        int b_ = mbase >> 10, t_ = mbase & 1023;
#pragma unroll
        for (int nt2 = 0; nt2 < 4; ++nt2) {
            int n = n0 + wn * 64 + nt2 * 16 + l15;
            int gate = n >> 10, u = n & 1023;
            float bv = bias[n];
            s16x4 pk;
            pk[0] = (short)f2bf(acc[mt2][nt2][0] + bv);
            pk[1] = (short)f2bf(acc[mt2][nt2][1] + bv);
            pk[2] = (short)f2bf(acc[mt2][nt2][2] + bv);
            pk[3] = (short)f2bf(acc[mt2][nt2][3] + bv);
            *(s16x4*)(gT + (((size_t)(gate * 32 + b_) << 10) + (size_t)u) * 1024 + t_) = pk;
        }
    }
}

// ---------------- sequential scan ----------------
// thread = one (b,u). gT bf16 [4][B][U][T] (t contiguous); h f32 [B,T,U].
// 4-deep ring of 16-B (8-timestep) loads per gate => 16 outstanding 1KB wave-loads.
__global__ __launch_bounds__(64) void scan_kernel(const unsigned short* __restrict__ gT,
                                                  const float* __restrict__ c0,
                                                  const float* __restrict__ Vr,
                                                  const float* __restrict__ Vf,
                                                  float* __restrict__ h) {
    int tid = blockIdx.x * 64 + threadIdx.x;    // 0..32767
    int b = tid >> 10, u = tid & 1023;
    const size_t GSTRIDE = (size_t)32 * 1024 * 1024;   // one gate plane
    const unsigned short* p1 = gT + ((size_t)(b << 10) + u) * 1024;
    const unsigned short* p2 = p1 + GSTRIDE;
    const unsigned short* p3 = p2 + GSTRIDE;
    const unsigned short* p4 = p3 + GSTRIDE;
    float* hb = h + ((size_t)b << 20) + u;
    float c = c0[(b << 10) + u];
    float vf = Vf[u], vr = Vr[u];

    short8 r1[4], r2[4], r3[4], r4[4];
#pragma unroll
    for (int i = 0; i < 4; ++i) {
        r1[i] = *(const short8*)(p1 + i * 8);
        r2[i] = *(const short8*)(p2 + i * 8);
        r3[i] = *(const short8*)(p3 + i * 8);
        r4[i] = *(const short8*)(p4 + i * 8);
    }
    for (int tb = 0; tb < 1024; tb += 32) {
#pragma unroll
        for (int s = 0; s < 4; ++s) {
            short8 a1 = r1[s], a2 = r2[s], a3 = r3[s], a4 = r4[s];
            int tp = tb + 32 + s * 8;                  // prefetch 4 chunks ahead
            if (tp < 1024) {
                r1[s] = *(const short8*)(p1 + tp);
                r2[s] = *(const short8*)(p2 + tp);
                r3[s] = *(const short8*)(p3 + tp);
                r4[s] = *(const short8*)(p4 + tp);
            }
            int t0 = tb + s * 8;
#pragma unroll
            for (int i = 0; i < 8; ++i) {
                float x1 = bf2f((unsigned short)a1[i]);
                float x2 = bf2f((unsigned short)a2[i]);
                float x3 = bf2f((unsigned short)a3[i]);
                float x4 = bf2f((unsigned short)a4[i]);
                float f  = sigmoid_f(x1 + vf * c);
                float cn = fmaf(f, c - x2, x2);        // f*c + (1-f)*a2
                float rr = sigmoid_f(x3 + vr * c);     // uses c_{t-1}
                float hv = fmaf(rr, cn - x4, x4);      // r*c_new + (1-r)*a4
                c = cn;
                hb[(size_t)(t0 + i) << 10] = hv;
            }
        }
    }
}

extern "C" void kernel_launch(void* const* d_in, const int* in_sizes, int n_in,
                              void* d_out, int out_size, void* d_ws, size_t ws_size,
                              hipStream_t stream) {
    const float* x  = (const float*)d_in[0];
    // d_in[1] = h0 (unused by reference)
    const float* c0 = (const float*)d_in[2];
    const float* W  = (const float*)d_in[3];
    const float* b  = (const float*)d_in[4];
    const float* Vr = (const float*)d_in[5];
    const float* Vf = (const float*)d_in[6];
    float* h = (float*)d_out;

    char* ws = (char*)d_ws;
    unsigned short* xb = (unsigned short*)ws;                         // 64 MB
    unsigned short* wt = (unsigned short*)(ws + (size_t)67108864);    // 8 MB
    unsigned short* gT = (unsigned short*)(ws + (size_t)75497472);    // 256 MB

    cvt_x_kernel<<<16384, 256, 0, stream>>>(x, xb);
    cvt_w_kernel<<<1024, 256, 0, stream>>>(W, wt);
    gemm_kernel<<<8192, 256, 0, stream>>>(xb, wt, b, gT);
    scan_kernel<<<512, 64, 0, stream>>>(gT, c0, Vr, Vf, h);
}